// Round 14
// baseline (16678.960 us; speedup 1.0000x reference)
//
#include <hip/hip_runtime.h>
#include <hip/hip_bf16.h>
#include <math.h>

#define B_     1024
#define VOCAB_ 130
#define EOS_   129

// Output FLOAT32 element offsets:
//   inv_features  @ 0        (24576)
//   inv_class_emb @ 24576    (901120)
//   str_emb       @ 925696   (72089600)
#define OUT_CLS_F  24576
#define OUT_STR_F  925696

// Workspace (float offsets): POOL 1024*32 | CNT 1024 | HC 1024*16 | diag
#define OFF_POOL 0
#define OFF_CNT  32768
#define OFF_HC   33792
#define OFF_DIAG 50176

static __device__ const int d_MAP[19] =
    {128,93,41,91,61,34,40,37,33,63,43,47,36,42,96,48,95,46,128};

__device__ __forceinline__ int badf(float v) {
    return (v != v) || (fabsf(v) > 1e30f);
}

// ---------------- k1: f32 gathers (str_emb with EOS, inv_class_emb), float4
__global__ void k1_embed(const int* oclass, const int* strs,
                         const float* emb, float* out)
{
    __shared__ __align__(16) float embF[VOCAB_ * 20];  // f32 rows, pitch 20
    __shared__ int chs[4 * 80];
    int bi = blockIdx.x, tid = threadIdx.x;

    for (int i = tid; i < VOCAB_ * 16; i += 256) {
        int r = i >> 4, c = i & 15;
        embF[r * 20 + c] = (r == 0) ? 0.f : emb[i];   // padding_idx=0
    }

    if (bi < 14080) {
        // 4 strings per block, one per wave
        int w = tid >> 6, lane = tid & 63;
        int s = bi * 4 + w;
        const int* cp = strs + (long)s * 80;
        chs[w * 80 + lane] = cp[lane];
        if (lane < 16) chs[w * 80 + 64 + lane] = cp[64 + lane];
        __syncthreads();
        int L = 0;
        for (int t = 0; t < 80; ++t) L += (chs[w * 80 + t] != 0);
        __syncthreads();
        if (lane == L) chs[w * 80 + lane] = EOS_;
        if (lane < 16 && (64 + lane) == L) chs[w * 80 + 64 + lane] = EOS_;
        __syncthreads();
        // 80 rows x 16 f32 = 320 float4 per string
        float4* dst = (float4*)(out + OUT_STR_F + (long)s * 1280);
        #pragma unroll
        for (int it = 0; it < 5; ++it) {
            int q = it * 64 + lane;
            int row = q >> 2, part = q & 3;
            int ch = chs[w * 80 + row];
            dst[q] = *(const float4*)&embF[ch * 20 + part * 4];
        }
    } else {
        __syncthreads();
        // inv_class_emb: 225280 float4 over 880 blocks x 256 threads
        int q = (bi - 14080) * 256 + tid;
        int bs = q >> 2, part = q & 3;
        int c = d_MAP[oclass[bs]];                 // never row 0
        float4* dst = (float4*)(out + OUT_CLS_F);
        dst[q] = *(const float4*)&embF[c * 20 + part * 4];
    }
}

// ---------------- k2: GRU fwd/bwd + class RNN (f32 weights direct from d_in)
__global__ void k2_rnn(const int* oclass, const int* strs, const float* emb,
                       const float* WihF, const float* WhhF,
                       const float* bihF, const float* bhhF,
                       const float* WihB, const float* WhhB,
                       const float* bihB, const float* bhhB,
                       const float* rWih, const float* rWhh,
                       const float* rbih, const float* rbhh,
                       float* ws)
{
    __shared__ float embL[VOCAB_ * 17];   // padded rows
    __shared__ float Wl[1632];
    __shared__ int MAPl[19];
    int bi = blockIdx.x, tid = threadIdx.x;
    for (int i = tid; i < VOCAB_ * 16; i += 256) {
        int r = i >> 4, c = i & 15;
        embL[r * 17 + c] = (r == 0) ? 0.f : emb[i];   // padding row zeroed
    }
    if (tid < 19) MAPl[tid] = d_MAP[tid];

    if (bi < 440) {
        bool fwd = bi < 220;
        const float* Wih = fwd ? WihF : WihB;
        const float* Whh = fwd ? WhhF : WhhB;
        const float* bih = fwd ? bihF : bihB;
        const float* bhh = fwd ? bhhF : bhhB;
        for (int i = tid; i < 768; i += 256) { Wl[i] = Wih[i]; Wl[768 + i] = Whh[i]; }
        for (int i = tid; i < 48;  i += 256) { Wl[1536 + i] = bih[i]; Wl[1584 + i] = bhh[i]; }
        __syncthreads();

        int s = (fwd ? bi : bi - 220) * 256 + tid;
        const int* cp = strs + (long)s * 80;
        int L = 0;
        for (int t = 0; t < 80; ++t) L += (cp[t] != 0);

        if (L > 0) {
            float h[16];
            #pragma unroll
            for (int j = 0; j < 16; ++j) h[j] = 0.f;
            int base = fwd ? 0 : (L - 1);
            int stp  = fwd ? 1 : -1;
            for (int t = 0; t < L; ++t) {
                int c = cp[base + t * stp];
                float x[16];
                #pragma unroll
                for (int d = 0; d < 16; ++d) x[d] = embL[c * 17 + d];
                float hn[16];
                #pragma unroll
                for (int j = 0; j < 16; ++j) {
                    float ir  = Wl[1536 + j], iz  = Wl[1552 + j], inn = Wl[1568 + j];
                    float hr  = Wl[1584 + j], hz  = Wl[1600 + j], hn2 = Wl[1616 + j];
                    #pragma unroll
                    for (int d = 0; d < 16; ++d) {
                        ir  = fmaf(Wl[       j * 16 + d], x[d], ir);
                        iz  = fmaf(Wl[(16 + j) * 16 + d], x[d], iz);
                        inn = fmaf(Wl[(32 + j) * 16 + d], x[d], inn);
                        hr  = fmaf(Wl[768 +        j  * 16 + d], h[d], hr);
                        hz  = fmaf(Wl[768 + (16 + j) * 16 + d], h[d], hz);
                        hn2 = fmaf(Wl[768 + (32 + j) * 16 + d], h[d], hn2);
                    }
                    float r = 1.f / (1.f + expf(-(ir + hr)));
                    float z = 1.f / (1.f + expf(-(iz + hz)));
                    float n = tanhf(inn + r * hn2);
                    hn[j] = (1.f - z) * n + z * h[j];
                }
                #pragma unroll
                for (int j = 0; j < 16; ++j) h[j] = hn[j];
            }
            int b = s / 55;
            float* pool = ws + OFF_POOL + b * 32 + (fwd ? 0 : 16);
            #pragma unroll
            for (int j = 0; j < 16; ++j) atomicAdd(&pool[j], h[j]);
            if (fwd) atomicAdd(&ws[OFF_CNT + b], 1.f);
        }
    } else {
        for (int i = tid; i < 256; i += 256) { Wl[i] = rWih[i]; Wl[256 + i] = rWhh[i]; }
        for (int i = tid; i < 16;  i += 256) { Wl[512 + i] = rbih[i]; Wl[528 + i] = rbhh[i]; }
        __syncthreads();
        int b = (bi - 440) * 256 + tid;
        const int* op = oclass + (long)b * 55;
        int len = 0;
        for (int t = 0; t < 55; ++t) len += (op[t] != 18);
        float h[16];
        #pragma unroll
        for (int j = 0; j < 16; ++j) h[j] = 0.f;
        for (int t = 0; t < len; ++t) {
            int c = MAPl[op[t]];
            float x[16];
            #pragma unroll
            for (int d = 0; d < 16; ++d) x[d] = embL[c * 17 + d];
            float hn[16];
            #pragma unroll
            for (int j = 0; j < 16; ++j) {
                float a = Wl[512 + j] + Wl[528 + j];
                #pragma unroll
                for (int d = 0; d < 16; ++d) {
                    a = fmaf(Wl[      j * 16 + d], x[d], a);
                    a = fmaf(Wl[256 + j * 16 + d], h[d], a);
                }
                hn[j] = tanhf(a);
            }
            #pragma unroll
            for (int j = 0; j < 16; ++j) h[j] = hn[j];
        }
        #pragma unroll
        for (int j = 0; j < 16; ++j) ws[OFF_HC + b * 16 + j] = h[j];
    }
}

// ---------------- k3: fusion MLP (f32 in/out), conditional diagnostic
__global__ void k3_fuse(const float* fW1, const float* fb1,
                        const float* fW2, const float* fb2,
                        float* ws, float* out)
{
    int b = blockIdx.x * 256 + threadIdx.x;
    if (b >= B_) return;
    float inv = 1.f / (ws[OFF_CNT + b] + 1e-8f);
    float comb[48];
    #pragma unroll
    for (int j = 0; j < 16; ++j) comb[j] = ws[OFF_HC + b * 16 + j];
    #pragma unroll
    for (int j = 0; j < 32; ++j) comb[16 + j] = ws[OFF_POOL + b * 32 + j] * inv;

    float hid[16];
    #pragma unroll
    for (int o = 0; o < 16; ++o) {
        float v = fb1[o];
        #pragma unroll
        for (int i = 0; i < 48; ++i) v = fmaf(fW1[o * 48 + i], comb[i], v);
        hid[o] = v > 0.f ? v : 0.f;
    }
    #pragma unroll
    for (int o = 0; o < 24; ++o) {
        float v = fb2[o];
        #pragma unroll
        for (int i = 0; i < 16; ++i) v = fmaf(fW2[o * 16 + i], hid[i], v);
        out[b * 24 + o] = v;
    }

    if (b == 0) {   // conditional diagnostic: silent on success
        int bb = 0;
        if (!badf(ws[OFF_POOL]))    bb |= 1;
        if (!badf(ws[OFF_HC]))      bb |= 2;
        if (ws[OFF_CNT] > 0.5f)     bb |= 4;
        if (bb != 7) {
            float code = 16384.f + 128.f * (float)bb;
            #pragma unroll
            for (int i = 4; i < 12; ++i) out[i] = code;
        }
    }
}

// ------------------------------------------------------------------- launch
extern "C" void kernel_launch(void* const* d_in, const int* in_sizes, int n_in,
                              void* d_out, int out_size, void* d_ws, size_t ws_size,
                              hipStream_t stream)
{
    const int*   oclass = (const int*)d_in[0];
    const int*   strs   = (const int*)d_in[1];
    const float* emb    = (const float*)d_in[2];
    const float* rWih   = (const float*)d_in[3];
    const float* rWhh   = (const float*)d_in[4];
    const float* rbih   = (const float*)d_in[5];
    const float* rbhh   = (const float*)d_in[6];
    const float* gWihF  = (const float*)d_in[7];
    const float* gWhhF  = (const float*)d_in[8];
    const float* gbihF  = (const float*)d_in[9];
    const float* gbhhF  = (const float*)d_in[10];
    const float* gWihB  = (const float*)d_in[11];
    const float* gWhhB  = (const float*)d_in[12];
    const float* gbihB  = (const float*)d_in[13];
    const float* gbhhB  = (const float*)d_in[14];
    const float* fW1    = (const float*)d_in[15];
    const float* fb1    = (const float*)d_in[16];
    const float* fW2    = (const float*)d_in[17];
    const float* fb2    = (const float*)d_in[18];

    float* ws  = (float*)d_ws;
    float* out = (float*)d_out;

    // zero POOL + CNT accumulators (33792 floats)
    hipMemsetAsync(d_ws, 0, 33792 * sizeof(float), stream);

    k1_embed<<<14960, 256, 0, stream>>>(oclass, strs, emb, out);
    k2_rnn<<<444, 256, 0, stream>>>(oclass, strs, emb,
                                    gWihF, gWhhF, gbihF, gbhhF,
                                    gWihB, gWhhB, gbihB, gbhhB,
                                    rWih, rWhh, rbih, rbhh, ws);
    k3_fuse<<<4, 256, 0, stream>>>(fW1, fb1, fW2, fb2, ws, out);
}

// Round 15
// 1112.630 us; speedup vs baseline: 14.9906x; 14.9906x over previous
//
#include <hip/hip_runtime.h>
#include <hip/hip_bf16.h>
#include <math.h>

#define B_     1024
#define VOCAB_ 130
#define EOS_   129

// Output FLOAT32 element offsets:
//   inv_features @0 (24576) | inv_class_emb @24576 (901120) | str_emb @925696
#define OUT_CLS_F  24576
#define OUT_STR_F  925696

// Workspace (float offsets): POOL 1024*32 | CNT 1024 | HC 1024*16
#define OFF_POOL 0
#define OFF_CNT  32768
#define OFF_HC   33792

static __device__ const int d_MAP[19] =
    {128,93,41,91,61,34,40,37,33,63,43,47,36,42,96,48,95,46,128};

__device__ __forceinline__ float sigm_(float x){
    return __builtin_amdgcn_rcpf(1.f + __builtin_amdgcn_exp2f(-1.4426950408889634f * x));
}
__device__ __forceinline__ float tanh_(float x){
    return 2.f * __builtin_amdgcn_rcpf(1.f + __builtin_amdgcn_exp2f(-2.8853900817779268f * x)) - 1.f;
}
__device__ __forceinline__ int badf(float v) {
    return (v != v) || (fabsf(v) > 1e30f);
}

// ---------------- k1: f32 gathers (str_emb with EOS, inv_class_emb), float4
__global__ void k1_embed(const int* oclass, const int* strs,
                         const float* emb, float* out)
{
    __shared__ __align__(16) float embF[VOCAB_ * 20];  // f32 rows, pitch 20
    __shared__ int chs[4 * 80];
    int bi = blockIdx.x, tid = threadIdx.x;

    for (int i = tid; i < VOCAB_ * 16; i += 256) {
        int r = i >> 4, c = i & 15;
        embF[r * 20 + c] = (r == 0) ? 0.f : emb[i];   // padding_idx=0
    }

    if (bi < 14080) {
        int w = tid >> 6, lane = tid & 63;
        int s = bi * 4 + w;
        const int* cp = strs + (long)s * 80;
        chs[w * 80 + lane] = cp[lane];
        if (lane < 16) chs[w * 80 + 64 + lane] = cp[64 + lane];
        __syncthreads();
        int L = 0;
        for (int t = 0; t < 80; ++t) L += (chs[w * 80 + t] != 0);
        __syncthreads();
        if (lane == L) chs[w * 80 + lane] = EOS_;
        if (lane < 16 && (64 + lane) == L) chs[w * 80 + 64 + lane] = EOS_;
        __syncthreads();
        float4* dst = (float4*)(out + OUT_STR_F + (long)s * 1280);
        #pragma unroll
        for (int it = 0; it < 5; ++it) {
            int q = it * 64 + lane;
            int row = q >> 2, part = q & 3;
            int ch = chs[w * 80 + row];
            dst[q] = *(const float4*)&embF[ch * 20 + part * 4];
        }
    } else {
        __syncthreads();
        int q = (bi - 14080) * 256 + tid;
        int bs = q >> 2, part = q & 3;
        int c = d_MAP[oclass[bs]];
        float4* dst = (float4*)(out + OUT_CLS_F);
        dst[q] = *(const float4*)&embF[c * 20 + part * 4];
    }
}

// ---------------- k2: GRU fwd/bwd (gi-table in LDS, Whh via s_load) + class RNN
__global__ __launch_bounds__(256, 2) void k2_rnn(
    const int* oclass, const int* strs, const float* emb,
    const float* __restrict__ WihF, const float* __restrict__ WhhF,
    const float* __restrict__ bihF, const float* __restrict__ bhhF,
    const float* __restrict__ WihB, const float* __restrict__ WhhB,
    const float* __restrict__ bihB, const float* __restrict__ bhhB,
    const float* __restrict__ rWih, const float* __restrict__ rWhh,
    const float* __restrict__ rbih, const float* __restrict__ rbhh,
    float* ws)
{
    __shared__ float embL[VOCAB_ * 16];                 // 8.3 KB
    __shared__ __align__(16) float T[VOCAB_ * 52];      // 27 KB gi-table, pitch 52
    int bi = blockIdx.x, tid = threadIdx.x;

    if (bi < 440) {
        bool fwd = bi < 220;
        const float* __restrict__ Wih = fwd ? WihF : WihB;
        const float* __restrict__ Whh = fwd ? WhhF : WhhB;
        const float* __restrict__ bih = fwd ? bihF : bihB;
        const float* __restrict__ bhh = fwd ? bhhF : bhhB;

        for (int i = tid; i < VOCAB_ * 16; i += 256)
            embL[i] = (i < 16) ? 0.f : emb[i];          // padding row 0
        __syncthreads();
        // T[c][j] = Wih_j . emb[c] + bih[j] (+ bhh[j] for j<32; bhh_n stays in r*(.))
        for (int i = tid; i < VOCAB_ * 48; i += 256) {
            int c = i / 48, j = i - c * 48;
            float v = bih[j] + ((j < 32) ? bhh[j] : 0.f);
            #pragma unroll
            for (int d = 0; d < 16; ++d)
                v = fmaf(Wih[j * 16 + d], embL[c * 16 + d], v);
            T[c * 52 + j] = v;
        }
        __syncthreads();

        float bn[16];
        #pragma unroll
        for (int j = 0; j < 16; ++j) bn[j] = bhh[32 + j];   // uniform s_loads

        int s = (fwd ? bi : bi - 220) * 256 + tid;
        const int* cp = strs + (long)s * 80;
        int L = 0;
        for (int t = 0; t < 80; ++t) L += (cp[t] != 0);

        if (L > 0) {
            float h[16];
            #pragma unroll
            for (int j = 0; j < 16; ++j) h[j] = 0.f;
            int base = fwd ? 0 : (L - 1);
            int stp  = fwd ? 1 : -1;
            int c = cp[base];
            for (int t = 0; t < L; ++t) {
                int cn = (t + 1 < L) ? cp[base + (t + 1) * stp] : 0;  // prefetch
                float Trow[48];
                #pragma unroll
                for (int q = 0; q < 12; ++q)
                    *(float4*)&Trow[4 * q] = *(const float4*)&T[c * 52 + 4 * q];
                float hn[16];
                #pragma unroll
                for (int j = 0; j < 16; ++j) {
                    float ar = 0.f, az = 0.f, an = bn[j];
                    #pragma unroll
                    for (int d = 0; d < 16; ++d) {
                        ar = fmaf(Whh[       j * 16 + d], h[d], ar);
                        az = fmaf(Whh[256 + j * 16 + d], h[d], az);
                        an = fmaf(Whh[512 + j * 16 + d], h[d], an);
                    }
                    float r = sigm_(Trow[j]      + ar);
                    float z = sigm_(Trow[16 + j] + az);
                    float n = tanh_(Trow[32 + j] + r * an);
                    hn[j] = (1.f - z) * n + z * h[j];
                }
                #pragma unroll
                for (int j = 0; j < 16; ++j) h[j] = hn[j];
                c = cn;
            }
            int b = s / 55;
            float* pool = ws + OFF_POOL + b * 32 + (fwd ? 0 : 16);
            #pragma unroll
            for (int j = 0; j < 16; ++j) atomicAdd(&pool[j], h[j]);
            if (fwd) atomicAdd(&ws[OFF_CNT + b], 1.f);
        }
    } else {
        // class RNN: fold T2[o][j] = rWih_j . emb[MAP[o]] + rbih[j] + rbhh[j]
        for (int i = tid; i < VOCAB_ * 16; i += 256)
            embL[i] = (i < 16) ? 0.f : emb[i];
        __syncthreads();
        for (int i = tid; i < 19 * 16; i += 256) {
            int o = i >> 4, j = i & 15;
            int c = d_MAP[o];
            float v = rbih[j] + rbhh[j];
            #pragma unroll
            for (int d = 0; d < 16; ++d)
                v = fmaf(rWih[j * 16 + d], embL[c * 16 + d], v);
            T[o * 16 + j] = v;
        }
        __syncthreads();

        int b = (bi - 440) * 256 + tid;
        const int* op = oclass + (long)b * 55;
        int len = 0;
        for (int t = 0; t < 55; ++t) len += (op[t] != 18);
        float h[16];
        #pragma unroll
        for (int j = 0; j < 16; ++j) h[j] = 0.f;
        for (int t = 0; t < len; ++t) {
            int o = op[t];
            float hn[16];
            #pragma unroll
            for (int j = 0; j < 16; ++j) {
                float a = T[o * 16 + j];
                #pragma unroll
                for (int d = 0; d < 16; ++d)
                    a = fmaf(rWhh[j * 16 + d], h[d], a);
                hn[j] = tanh_(a);
            }
            #pragma unroll
            for (int j = 0; j < 16; ++j) h[j] = hn[j];
        }
        #pragma unroll
        for (int j = 0; j < 16; ++j) ws[OFF_HC + b * 16 + j] = h[j];
    }
}

// ---------------- k3: fusion MLP (f32 in/out), conditional diagnostic
__global__ void k3_fuse(const float* fW1, const float* fb1,
                        const float* fW2, const float* fb2,
                        float* ws, float* out)
{
    int b = blockIdx.x * 256 + threadIdx.x;
    if (b >= B_) return;
    float inv = 1.f / (ws[OFF_CNT + b] + 1e-8f);
    float comb[48];
    #pragma unroll
    for (int j = 0; j < 16; ++j) comb[j] = ws[OFF_HC + b * 16 + j];
    #pragma unroll
    for (int j = 0; j < 32; ++j) comb[16 + j] = ws[OFF_POOL + b * 32 + j] * inv;

    float hid[16];
    #pragma unroll
    for (int o = 0; o < 16; ++o) {
        float v = fb1[o];
        #pragma unroll
        for (int i = 0; i < 48; ++i) v = fmaf(fW1[o * 48 + i], comb[i], v);
        hid[o] = v > 0.f ? v : 0.f;
    }
    #pragma unroll
    for (int o = 0; o < 24; ++o) {
        float v = fb2[o];
        #pragma unroll
        for (int i = 0; i < 16; ++i) v = fmaf(fW2[o * 16 + i], hid[i], v);
        out[b * 24 + o] = v;
    }

    if (b == 0) {   // silent on success
        int bb = 0;
        if (!badf(ws[OFF_POOL]))    bb |= 1;
        if (!badf(ws[OFF_HC]))      bb |= 2;
        if (ws[OFF_CNT] > 0.5f)     bb |= 4;
        if (bb != 7) {
            float code = 16384.f + 128.f * (float)bb;
            #pragma unroll
            for (int i = 4; i < 12; ++i) out[i] = code;
        }
    }
}

// ------------------------------------------------------------------- launch
extern "C" void kernel_launch(void* const* d_in, const int* in_sizes, int n_in,
                              void* d_out, int out_size, void* d_ws, size_t ws_size,
                              hipStream_t stream)
{
    const int*   oclass = (const int*)d_in[0];
    const int*   strs   = (const int*)d_in[1];
    const float* emb    = (const float*)d_in[2];
    const float* rWih   = (const float*)d_in[3];
    const float* rWhh   = (const float*)d_in[4];
    const float* rbih   = (const float*)d_in[5];
    const float* rbhh   = (const float*)d_in[6];
    const float* gWihF  = (const float*)d_in[7];
    const float* gWhhF  = (const float*)d_in[8];
    const float* gbihF  = (const float*)d_in[9];
    const float* gbhhF  = (const float*)d_in[10];
    const float* gWihB  = (const float*)d_in[11];
    const float* gWhhB  = (const float*)d_in[12];
    const float* gbihB  = (const float*)d_in[13];
    const float* gbhhB  = (const float*)d_in[14];
    const float* fW1    = (const float*)d_in[15];
    const float* fb1    = (const float*)d_in[16];
    const float* fW2    = (const float*)d_in[17];
    const float* fb2    = (const float*)d_in[18];

    float* ws  = (float*)d_ws;
    float* out = (float*)d_out;

    hipMemsetAsync(d_ws, 0, 33792 * sizeof(float), stream);

    k1_embed<<<14960, 256, 0, stream>>>(oclass, strs, emb, out);
    k2_rnn<<<444, 256, 0, stream>>>(oclass, strs, emb,
                                    gWihF, gWhhF, gbihF, gbhhF,
                                    gWihB, gWhhB, gbihB, gbhhB,
                                    rWih, rWhh, rbih, rbhh, ws);
    k3_fuse<<<4, 256, 0, stream>>>(fW1, fb1, fW2, fb2, ws, out);
}